// Round 1
// baseline (241.384 us; speedup 1.0000x reference)
//
#include <hip/hip_runtime.h>

// CapsuleLayer dynamic routing, MI355X. R4:
//  - 512-thread blocks, grid=256 (1 block/CU): each wave owns 4 b's, 8 waves
//    cover all B=32, so each i-group's 256KB W tile is fetched ONCE per sweep
//    (R3 fetched it twice: bh batch-halves on different XCDs).
//  - T14 issue-early/write-late W staging: next i's 4 global float4 loads are
//    issued right after the consume barrier, so L3/HBM latency hides under the
//    current i's 512-FMA compute instead of sitting between the two barriers.
//  - ii loop kept rolled (#pragma unroll 1) to stay I$-resident.
//
// Lane layout (sweep): lane l owns d = l>>1, h = l&1, outputs
// o = d*16 + h*8 + j (j=0..7).
//   - a-half combine: shfl_xor(.,1); softmax over D: shfl_xor {2,4,8,16,32}
// LDS W layout: sW[(j>>2)*4096 + k*256 + (d*2+h)*4 + (j&3)] ->
//   hot-loop read = 2x ds_read_b128 per k at lane*16B (conflict-free),
//   staging store = 1x ds_write_b128 per loaded global float4 (2-way, free).
// x is loaded via wave-uniform (SGPR) scalar loads.

#define B_  32
#define I_  2048
#define K_  16
#define O_  512
#define NG_ 256   // i-groups (partial-buffer leading dim)
#define IC_ 8     // i's per group

template<int PASS>
__global__ __launch_bounds__(512, 2)
void sweep_kernel(const float* __restrict__ x, const float* __restrict__ W,
                  const float* __restrict__ act0_g, const float* __restrict__ act1_g,
                  float* __restrict__ partial)
{
    const int tid  = threadIdx.x;
    const int lane = tid & 63;
    const int wave = tid >> 6;              // 0..7
    const int ig   = blockIdx.x;            // 0..255
    const int d    = lane >> 1;             // 0..31
    const int h    = lane & 1;
    const int obase = d * 16 + h * 8;       // lane's first o

    // wave-uniform batch base (forces SGPR so x loads go scalar)
    const int wv    = __builtin_amdgcn_readfirstlane(wave);
    const int bbase = wv * 4;               // 8 waves x 4 b = 32 b

    __shared__ float sW[K_ * O_];           // 32 KB, permuted W[i] tile

    float facc[4][8];
    #pragma unroll
    for (int bb = 0; bb < 4; ++bb)
        #pragma unroll
        for (int j = 0; j < 8; ++j) facc[bb][j] = 0.f;

    float a0[4][8], a1[4][8];
    if (PASS >= 1) {
        #pragma unroll
        for (int bb = 0; bb < 4; ++bb) {
            const float4* p = (const float4*)(act0_g + (bbase + bb) * O_ + obase);
            float4 f0 = p[0], f1 = p[1];
            a0[bb][0]=f0.x; a0[bb][1]=f0.y; a0[bb][2]=f0.z; a0[bb][3]=f0.w;
            a0[bb][4]=f1.x; a0[bb][5]=f1.y; a0[bb][6]=f1.z; a0[bb][7]=f1.w;
        }
    }
    if (PASS == 2) {
        #pragma unroll
        for (int bb = 0; bb < 4; ++bb) {
            const float4* p = (const float4*)(act1_g + (bbase + bb) * O_ + obase);
            float4 f0 = p[0], f1 = p[1];
            a1[bb][0]=f0.x; a1[bb][1]=f0.y; a1[bb][2]=f0.z; a1[bb][3]=f0.w;
            a1[bb][4]=f1.x; a1[bb][5]=f1.y; a1[bb][6]=f1.z; a1[bb][7]=f1.w;
        }
    }

    // T14: prefetch W[i0] into registers before the loop
    float4 wreg[4];
    {
        const float4* Wg = (const float4*)(W + (size_t)(ig * IC_) * (K_ * O_));
        #pragma unroll
        for (int q = 0; q < 4; ++q) wreg[q] = Wg[tid + 512 * q];
    }

    #pragma unroll 1
    for (int ii = 0; ii < IC_; ++ii) {
        const int i = ig * IC_ + ii;
        __syncthreads();   // prior iteration's LDS reads done
        // write prefetched W[i] permuted: 2048 float4s, 4/thread, ds_write_b128
        {
            #pragma unroll
            for (int q = 0; q < 4; ++q) {
                const int f  = tid + 512 * q;
                const int e0 = 4 * f;
                const int k  = e0 >> 9;
                const int o  = e0 & (O_ - 1);
                const int dd = o >> 4;
                const int aa = o & 15;
                const int hh = aa >> 3;
                const int jq = (aa >> 2) & 1;
                *(float4*)&sW[jq * 4096 + k * 256 + (dd * 2 + hh) * 4] = wreg[q];
            }
        }
        __syncthreads();
        // issue next i's W loads NOW; vmcnt wait lands at next ds_write,
        // latency hides under this iteration's compute
        if (ii + 1 < IC_) {
            const float4* Wg = (const float4*)(W + (size_t)(i + 1) * (K_ * O_));
            #pragma unroll
            for (int q = 0; q < 4; ++q) wreg[q] = Wg[tid + 512 * q];
        }

        // x for this wave's 4 b's: wave-uniform scalar loads (SGPRs)
        float xs[4][16];
        #pragma unroll
        for (int bb = 0; bb < 4; ++bb) {
            const float4* xp = (const float4*)(x + ((size_t)(bbase + bb) * I_ + i) * K_);
            #pragma unroll
            for (int q = 0; q < 4; ++q) {
                float4 v = xp[q];
                xs[bb][4*q+0]=v.x; xs[bb][4*q+1]=v.y; xs[bb][4*q+2]=v.z; xs[bb][4*q+3]=v.w;
            }
        }

        // V[bb][j]: 2 ds_read_b128 per k
        float V[4][8];
        #pragma unroll
        for (int bb = 0; bb < 4; ++bb)
            #pragma unroll
            for (int j = 0; j < 8; ++j) V[bb][j] = 0.f;
        #pragma unroll
        for (int k = 0; k < K_; ++k) {
            const float4 w0 = *(const float4*)&sW[k * 256 + lane * 4];
            const float4 w1 = *(const float4*)&sW[4096 + k * 256 + lane * 4];
            const float w[8] = {w0.x, w0.y, w0.z, w0.w, w1.x, w1.y, w1.z, w1.w};
            #pragma unroll
            for (int bb = 0; bb < 4; ++bb) {
                const float xb = xs[bb][k];
                #pragma unroll
                for (int j = 0; j < 8; ++j) V[bb][j] = fmaf(xb, w[j], V[bb][j]);
            }
        }

        #pragma unroll
        for (int bb = 0; bb < 4; ++bb) {
            if (PASS == 0) {
                #pragma unroll
                for (int j = 0; j < 8; ++j) facc[bb][j] += V[bb][j];
            } else {
                float p0 = 0.f;
                #pragma unroll
                for (int j = 0; j < 8; ++j) p0 = fmaf(V[bb][j], a0[bb][j], p0);
                p0 += __shfl_xor(p0, 1);        // combine the two a-halves
                float lg = p0;
                if (PASS == 2) {
                    float p1 = 0.f;
                    #pragma unroll
                    for (int j = 0; j < 8; ++j) p1 = fmaf(V[bb][j], a1[bb][j], p1);
                    p1 += __shfl_xor(p1, 1);
                    lg += p1;
                }
                // softmax over 32 d's (no max-sub: |logits| small, f32-safe)
                const float e = __expf(lg);
                float s = e;
                s += __shfl_xor(s, 2);
                s += __shfl_xor(s, 4);
                s += __shfl_xor(s, 8);
                s += __shfl_xor(s, 16);
                s += __shfl_xor(s, 32);
                const float r = e * __builtin_amdgcn_rcpf(s);
                #pragma unroll
                for (int j = 0; j < 8; ++j)
                    facc[bb][j] = fmaf(r, V[bb][j], facc[bb][j]);
            }
        }
    }

    // flush per-(ig) partials
    #pragma unroll
    for (int bb = 0; bb < 4; ++bb) {
        const int b = bbase + bb;
        float4* dst = (float4*)(partial + ((size_t)ig * B_ + b) * O_ + obase);
        dst[0] = make_float4(facc[bb][0], facc[bb][1], facc[bb][2], facc[bb][3]);
        dst[1] = make_float4(facc[bb][4], facc[bb][5], facc[bb][6], facc[bb][7]);
    }
}

// sum NG_ partials -> *scale + bias -> squash over A -> out
// 512 wgs x 256 thr; wg covers 32 g's; 8 w-slices of 32 reduced via LDS.
__global__ __launch_bounds__(256)
void reduce_squash(const float* __restrict__ partial, const float* __restrict__ bias,
                   float scale, float* __restrict__ out)
{
    const int t  = threadIdx.x;
    const int g  = blockIdx.x * 32 + (t & 31);   // b*512 + o
    const int sl = t >> 5;                       // w-slice 0..7
    float s = 0.f;
    #pragma unroll
    for (int w = sl * 32; w < sl * 32 + 32; ++w)
        s += partial[(size_t)w * (B_ * O_) + g];
    __shared__ float red[256];
    red[t] = s;
    __syncthreads();
    if (t < 32) {
        float v = red[t];
        #pragma unroll
        for (int r = 1; r < 8; ++r) v += red[t + 32 * r];
        const float p = fmaf(v, scale, bias[g & (O_ - 1)]);
        float nn = p * p;
        nn += __shfl_xor(nn, 1);
        nn += __shfl_xor(nn, 2);
        nn += __shfl_xor(nn, 4);
        nn += __shfl_xor(nn, 8);
        out[g] = p * sqrtf(nn) / (1.f + nn);
    }
}

extern "C" void kernel_launch(void* const* d_in, const int* in_sizes, int n_in,
                              void* d_out, int out_size, void* d_ws, size_t ws_size,
                              hipStream_t stream) {
    const float* x    = (const float*)d_in[0];   // [32,2048,16]
    const float* W    = (const float*)d_in[1];   // [2048,16,512]
    const float* bias = (const float*)d_in[2];   // [512]
    float* out = (float*)d_out;                  // [32,512]

    float* partial = (float*)d_ws;                       // NG_*32*512 f32 = 16.8 MB
    float* act0    = partial + (size_t)NG_ * B_ * O_;    // 64 KB
    float* act1    = act0 + B_ * O_;                     // 64 KB

    sweep_kernel<0><<<NG_, 512, 0, stream>>>(x, W, nullptr, nullptr, partial);
    reduce_squash<<<512, 256, 0, stream>>>(partial, bias, 1.f / 32.f, act0);
    sweep_kernel<1><<<NG_, 512, 0, stream>>>(x, W, act0, nullptr, partial);
    reduce_squash<<<512, 256, 0, stream>>>(partial, bias, 1.f, act1);
    sweep_kernel<2><<<NG_, 512, 0, stream>>>(x, W, act0, act1, partial);
    reduce_squash<<<512, 256, 0, stream>>>(partial, bias, 1.f, out);
}

// Round 2
// 188.800 us; speedup vs baseline: 1.2785x; 1.2785x over previous
//
#include <hip/hip_runtime.h>

// CapsuleLayer dynamic routing, MI355X. R5:
//  - back to 512 blocks x 256 threads (2 blocks/CU -> inter-block overlap;
//    R4's 1 block/CU serialized everything: VALUBusy 11%, 59us sweeps).
//  - double-buffered LDS W tile + ONE barrier per ii: stage W[i+1] into the
//    other half via global_load_lds while computing W[i]. __syncthreads()'s
//    implicit vmcnt(0) drains each wave's own stage loads right before use.
//  - global_load_lds dwordx4 with PRE-SWIZZLED per-lane source addresses:
//    LDS slot s <-> global float4 f is a bit-permutation
//    (s = 1024*jq + 64*k + 2*dd + hh), so HW writes lane-linear LDS while the
//    source address carries the permutation. No ds_writes, no wreg round-trip,
//    zero write-side bank conflicts (R4 had 524288 = 1/ds_write_b128).
//  - XCD-pair swizzle: both bh-blocks of an i-group land on the same XCD
//    (xcd = bid&7 round-robin), so the 256KB W tile is fetched from HBM once
//    per pair and the second block hits that XCD's L2.
//
// Lane layout (sweep): lane l owns d = l>>1, h = l&1, outputs
// o = d*16 + h*8 + j (j=0..7).
//   - a-half combine: shfl_xor(.,1); softmax over D: shfl_xor {2,4,8,16,32}
// LDS W layout (per half): float idx = jq*4096 + k*256 + (d*2+h)*4 + (j&3)
//   hot-loop read = 2x ds_read_b128 per k at lane*16B (2-way in quarter-wave,
//   free). x is loaded via wave-uniform (SGPR) scalar loads.

#define B_  32
#define I_  2048
#define K_  16
#define O_  512
#define NG_ 256   // i-groups (partial-buffer leading dim)
#define IC_ 8     // i's per group

#define GLB(p)  ((const __attribute__((address_space(1))) void*)(p))
#define LDSP(p) ((__attribute__((address_space(3))) void*)(p))

template<int PASS>
__global__ __launch_bounds__(256, 2)
void sweep_kernel(const float* __restrict__ x, const float* __restrict__ W,
                  const float* __restrict__ act0_g, const float* __restrict__ act1_g,
                  float* __restrict__ partial)
{
    const int tid  = threadIdx.x;
    const int lane = tid & 63;
    const int wave = tid >> 6;              // 0..3
    const int bid  = blockIdx.x;
    // XCD-pair swizzle: xcd = bid&7 (round-robin), pair differs only in bit 3
    const int ig   = (bid & 7) * 32 + (bid >> 4);   // 0..255
    const int bh   = (bid >> 3) & 1;                 // batch half
    const int d    = lane >> 1;             // 0..31
    const int h    = lane & 1;
    const int obase = d * 16 + h * 8;       // lane's first o

    // wave-uniform batch base (forces SGPR so x loads go scalar)
    const int wv    = __builtin_amdgcn_readfirstlane(wave);
    const int bbase = bh * 16 + wv * 4;

    __shared__ float sW[2][K_ * O_];        // 2 x 32 KB, permuted W[i] tiles

    // per-lane pre-swizzled source byte offsets: slot s -> global float4 f
    // s = 1024*jq + 64*k + (2*dd+hh); f bits: {f0=s10, f1=s0, f[6:2]=s[5:1],
    // f[10:7]=s[9:6]}  (verified bijection on [0,2048))
    int voff[8];
    #pragma unroll
    for (int c = 0; c < 8; ++c) {
        const int s = c * 256 + wave * 64 + lane;       // 16B slot index
        const int f = ((s >> 10) & 1) | ((s & 1) << 1)
                    | (((s >> 1) & 31) << 2) | (((s >> 6) & 15) << 7);
        voff[c] = f << 4;                               // byte offset
    }

    float facc[4][8];
    #pragma unroll
    for (int bb = 0; bb < 4; ++bb)
        #pragma unroll
        for (int j = 0; j < 8; ++j) facc[bb][j] = 0.f;

    float a0[4][8], a1[4][8];
    if (PASS >= 1) {
        #pragma unroll
        for (int bb = 0; bb < 4; ++bb) {
            const float4* p = (const float4*)(act0_g + (bbase + bb) * O_ + obase);
            float4 f0 = p[0], f1 = p[1];
            a0[bb][0]=f0.x; a0[bb][1]=f0.y; a0[bb][2]=f0.z; a0[bb][3]=f0.w;
            a0[bb][4]=f1.x; a0[bb][5]=f1.y; a0[bb][6]=f1.z; a0[bb][7]=f1.w;
        }
    }
    if (PASS == 2) {
        #pragma unroll
        for (int bb = 0; bb < 4; ++bb) {
            const float4* p = (const float4*)(act1_g + (bbase + bb) * O_ + obase);
            float4 f0 = p[0], f1 = p[1];
            a1[bb][0]=f0.x; a1[bb][1]=f0.y; a1[bb][2]=f0.z; a1[bb][3]=f0.w;
            a1[bb][4]=f1.x; a1[bb][5]=f1.y; a1[bb][6]=f1.z; a1[bb][7]=f1.w;
        }
    }

    // prologue: stage W[i0] into buf 0
    {
        const char* gb = (const char*)(W + (size_t)(ig * IC_) * (K_ * O_));
        #pragma unroll
        for (int c = 0; c < 8; ++c)
            __builtin_amdgcn_global_load_lds(GLB(gb + voff[c]),
                LDSP(&sW[0][(c * 256 + wave * 64) * 4]), 16, 0, 0);
    }

    #pragma unroll 1
    for (int ii = 0; ii < IC_; ++ii) {
        const int i = ig * IC_ + ii;
        // implicit s_waitcnt vmcnt(0): own stage loads drained; barrier:
        // everyone's drained -> buf[ii&1] fully staged, prior reads done.
        __syncthreads();
        // issue next tile's stage into the other half (latency hides under
        // this iteration's compute; drained at next barrier)
        if (ii + 1 < IC_) {
            const char* gb = (const char*)(W + (size_t)(i + 1) * (K_ * O_));
            float* nbuf = sW[(ii + 1) & 1];
            #pragma unroll
            for (int c = 0; c < 8; ++c)
                __builtin_amdgcn_global_load_lds(GLB(gb + voff[c]),
                    LDSP(&nbuf[(c * 256 + wave * 64) * 4]), 16, 0, 0);
        }
        const float* cbuf = sW[ii & 1];

        // x for this wave's 4 b's: wave-uniform scalar loads (SGPRs)
        float xs[4][16];
        #pragma unroll
        for (int bb = 0; bb < 4; ++bb) {
            const float4* xp = (const float4*)(x + ((size_t)(bbase + bb) * I_ + i) * K_);
            #pragma unroll
            for (int q = 0; q < 4; ++q) {
                float4 v = xp[q];
                xs[bb][4*q+0]=v.x; xs[bb][4*q+1]=v.y; xs[bb][4*q+2]=v.z; xs[bb][4*q+3]=v.w;
            }
        }

        // V[bb][j]: 2 ds_read_b128 per k
        float V[4][8];
        #pragma unroll
        for (int bb = 0; bb < 4; ++bb)
            #pragma unroll
            for (int j = 0; j < 8; ++j) V[bb][j] = 0.f;
        #pragma unroll
        for (int k = 0; k < K_; ++k) {
            const float4 w0 = *(const float4*)&cbuf[k * 256 + lane * 4];
            const float4 w1 = *(const float4*)&cbuf[4096 + k * 256 + lane * 4];
            const float w[8] = {w0.x, w0.y, w0.z, w0.w, w1.x, w1.y, w1.z, w1.w};
            #pragma unroll
            for (int bb = 0; bb < 4; ++bb) {
                const float xb = xs[bb][k];
                #pragma unroll
                for (int j = 0; j < 8; ++j) V[bb][j] = fmaf(xb, w[j], V[bb][j]);
            }
        }

        #pragma unroll
        for (int bb = 0; bb < 4; ++bb) {
            if (PASS == 0) {
                #pragma unroll
                for (int j = 0; j < 8; ++j) facc[bb][j] += V[bb][j];
            } else {
                float p0 = 0.f;
                #pragma unroll
                for (int j = 0; j < 8; ++j) p0 = fmaf(V[bb][j], a0[bb][j], p0);
                p0 += __shfl_xor(p0, 1);        // combine the two a-halves
                float lg = p0;
                if (PASS == 2) {
                    float p1 = 0.f;
                    #pragma unroll
                    for (int j = 0; j < 8; ++j) p1 = fmaf(V[bb][j], a1[bb][j], p1);
                    p1 += __shfl_xor(p1, 1);
                    lg += p1;
                }
                // softmax over 32 d's (no max-sub: |logits| small, f32-safe)
                const float e = __expf(lg);
                float s = e;
                s += __shfl_xor(s, 2);
                s += __shfl_xor(s, 4);
                s += __shfl_xor(s, 8);
                s += __shfl_xor(s, 16);
                s += __shfl_xor(s, 32);
                const float r = e * __builtin_amdgcn_rcpf(s);
                #pragma unroll
                for (int j = 0; j < 8; ++j)
                    facc[bb][j] = fmaf(r, V[bb][j], facc[bb][j]);
            }
        }
    }

    // flush per-(ig) partials
    #pragma unroll
    for (int bb = 0; bb < 4; ++bb) {
        const int b = bbase + bb;
        float4* dst = (float4*)(partial + ((size_t)ig * B_ + b) * O_ + obase);
        dst[0] = make_float4(facc[bb][0], facc[bb][1], facc[bb][2], facc[bb][3]);
        dst[1] = make_float4(facc[bb][4], facc[bb][5], facc[bb][6], facc[bb][7]);
    }
}

// sum NG_ partials -> *scale + bias -> squash over A -> out
// 512 wgs x 256 thr; wg covers 32 g's; 8 w-slices of 32 reduced via LDS.
__global__ __launch_bounds__(256)
void reduce_squash(const float* __restrict__ partial, const float* __restrict__ bias,
                   float scale, float* __restrict__ out)
{
    const int t  = threadIdx.x;
    const int g  = blockIdx.x * 32 + (t & 31);   // b*512 + o
    const int sl = t >> 5;                       // w-slice 0..7
    float s = 0.f;
    #pragma unroll
    for (int w = sl * 32; w < sl * 32 + 32; ++w)
        s += partial[(size_t)w * (B_ * O_) + g];
    __shared__ float red[256];
    red[t] = s;
    __syncthreads();
    if (t < 32) {
        float v = red[t];
        #pragma unroll
        for (int r = 1; r < 8; ++r) v += red[t + 32 * r];
        const float p = fmaf(v, scale, bias[g & (O_ - 1)]);
        float nn = p * p;
        nn += __shfl_xor(nn, 1);
        nn += __shfl_xor(nn, 2);
        nn += __shfl_xor(nn, 4);
        nn += __shfl_xor(nn, 8);
        out[g] = p * sqrtf(nn) / (1.f + nn);
    }
}

extern "C" void kernel_launch(void* const* d_in, const int* in_sizes, int n_in,
                              void* d_out, int out_size, void* d_ws, size_t ws_size,
                              hipStream_t stream) {
    const float* x    = (const float*)d_in[0];   // [32,2048,16]
    const float* W    = (const float*)d_in[1];   // [2048,16,512]
    const float* bias = (const float*)d_in[2];   // [512]
    float* out = (float*)d_out;                  // [32,512]

    float* partial = (float*)d_ws;                       // NG_*32*512 f32 = 16.8 MB
    float* act0    = partial + (size_t)NG_ * B_ * O_;    // 64 KB
    float* act1    = act0 + B_ * O_;                     // 64 KB

    sweep_kernel<0><<<NG_ * 2, 256, 0, stream>>>(x, W, nullptr, nullptr, partial);
    reduce_squash<<<512, 256, 0, stream>>>(partial, bias, 1.f / 32.f, act0);
    sweep_kernel<1><<<NG_ * 2, 256, 0, stream>>>(x, W, act0, nullptr, partial);
    reduce_squash<<<512, 256, 0, stream>>>(partial, bias, 1.f, act1);
    sweep_kernel<2><<<NG_ * 2, 256, 0, stream>>>(x, W, act0, act1, partial);
    reduce_squash<<<512, 256, 0, stream>>>(partial, bias, 1.f, out);
}